// Round 10
// baseline (228.039 us; speedup 1.0000x reference)
//
#include <hip/hip_runtime.h>

#define B_ 16
#define L_ 512
#define H_ 256
#define V_ 32000
#define HALF_ 128

typedef __attribute__((ext_vector_type(8))) short short8;
typedef __attribute__((ext_vector_type(4))) float floatx4;

__device__ __forceinline__ unsigned short f2bf(float x) {
  unsigned int u = __float_as_uint(x);
  unsigned int r = (u + 0x7FFFu + ((u >> 16) & 1u)) >> 16;
  return (unsigned short)r;
}

template <int CTRL>
__device__ __forceinline__ float dpp_xor_add(float x) {
  int y = __builtin_amdgcn_mov_dpp(__float_as_int(x), CTRL, 0xf, 0xf, true);
  return x + __int_as_float(y);
}

// butterfly sum over aligned 16-lane groups; ALL lanes get the result
__device__ __forceinline__ float redu16(float p) {
  p = dpp_xor_add<0xB1>(p);   // xor1
  p = dpp_xor_add<0x4E>(p);   // xor2
  p = dpp_xor_add<0x141>(p);  // row_half_mirror
  p = dpp_xor_add<0x140>(p);  // row_mirror
  return p;
}

// async global->LDS copy, 16B per lane, wave-uniform LDS base
__device__ __forceinline__ void async_cp16(const float* g, float* l) {
  __builtin_amdgcn_global_load_lds(
      (const __attribute__((address_space(1))) void*)g,
      (__attribute__((address_space(3))) void*)l, 16, 0, 0);
}

__device__ __forceinline__ float dot8t(const float* a, const float* b) {
  return ((a[0] * b[0] + a[1] * b[1]) + (a[2] * b[2] + a[3] * b[3])) +
         ((a[4] * b[4] + a[5] * b[5]) + (a[6] * b[6] + a[7] * b[7]));
}

// ---------------- prep: embedding gather (fp32+bf16) + weight bf16 conversion ----------------
__global__ __launch_bounds__(256) void prep_kernel(const int* __restrict__ seq,
                                                   const float* __restrict__ embed,
                                                   float* __restrict__ h,
                                                   unsigned short* __restrict__ hbf,
                                                   const float* __restrict__ W1,
                                                   const float* __restrict__ W2,
                                                   const float* __restrict__ Ws,
                                                   const float* __restrict__ We,
                                                   unsigned short* __restrict__ W1b,
                                                   unsigned short* __restrict__ W2b,
                                                   unsigned short* __restrict__ Wcb) {
  int blk = blockIdx.x;
  int tid = threadIdx.x;
  if (blk < 2048) {
    int token = blk * 4 + (tid >> 6);
    int lane = tid & 63;
    int row = seq[token];
    float4 v = ((const float4*)(embed + (size_t)row * H_))[lane];
    ((float4*)(h + (size_t)token * H_))[lane] = v;
    ushort4 o;
    o.x = f2bf(v.x); o.y = f2bf(v.y); o.z = f2bf(v.z); o.w = f2bf(v.w);
    *(ushort4*)(hbf + (size_t)token * H_ + lane * 4) = o;
  } else {
    int i = (blk - 2048) * 256 + tid;  // 0..327679
    if (i < 131072) W1b[i] = f2bf(W1[i]);
    else if (i < 262144) W2b[i - 131072] = f2bf(W2[i - 131072]);
    else if (i < 294912) Wcb[i - 262144] = f2bf(Ws[i - 262144]);
    else Wcb[i - 262144] = f2bf(We[i - 294912]);
  }
}

// ---------------- bf16 MFMA GEMM with global prefetch: C = act(A @ B^T + bias + Res) ----------------
template <int MT, bool RELU, bool BIAS, bool RES, bool OUT_BF16>
__global__ __launch_bounds__(256) void gemm_mfma(const unsigned short* __restrict__ A,
                                                 const unsigned short* __restrict__ Bw,
                                                 const float* __restrict__ bias,
                                                 const float* __restrict__ Res,
                                                 float* __restrict__ Cf,
                                                 unsigned short* __restrict__ Cb,
                                                 int M, int N, int K) {
  constexpr int FI = MT / 32;
  __shared__ unsigned short As[MT * 40];
  __shared__ unsigned short Bs[128 * 40];
  int tid = threadIdx.x;
  int wave = tid >> 6, lane = tid & 63;
  int wm = (wave >> 1) * (MT / 2), wn = (wave & 1) * 64;
  int quad = lane >> 4, l15 = lane & 15;
  int bm = blockIdx.y * MT, bn = blockIdx.x * 128;
  int sr = tid >> 2, sq = tid & 3;

  floatx4 zero = {0.f, 0.f, 0.f, 0.f};
  floatx4 acc[FI][4];
#pragma unroll
  for (int fi = 0; fi < FI; fi++)
#pragma unroll
    for (int fj = 0; fj < 4; fj++) acc[fi][fj] = zero;

  // prefetch chunk 0
  uint4 av0, av1, bv0, bv1;
  av0 = *(const uint4*)(A + (size_t)(bm + sr) * K + sq * 8);
  if (MT == 128) av1 = *(const uint4*)(A + (size_t)(bm + 64 + sr) * K + sq * 8);
  bv0 = *(const uint4*)(Bw + (size_t)(bn + sr) * K + sq * 8);
  bv1 = *(const uint4*)(Bw + (size_t)(bn + 64 + sr) * K + sq * 8);

  for (int k0 = 0; k0 < K; k0 += 32) {
    __syncthreads();
    *(uint4*)(As + sr * 40 + sq * 8) = av0;
    if (MT == 128) *(uint4*)(As + (64 + sr) * 40 + sq * 8) = av1;
    *(uint4*)(Bs + sr * 40 + sq * 8) = bv0;
    *(uint4*)(Bs + (64 + sr) * 40 + sq * 8) = bv1;
    __syncthreads();
    if (k0 + 32 < K) {  // prefetch next chunk while MFMAs run
      av0 = *(const uint4*)(A + (size_t)(bm + sr) * K + k0 + 32 + sq * 8);
      if (MT == 128) av1 = *(const uint4*)(A + (size_t)(bm + 64 + sr) * K + k0 + 32 + sq * 8);
      bv0 = *(const uint4*)(Bw + (size_t)(bn + sr) * K + k0 + 32 + sq * 8);
      bv1 = *(const uint4*)(Bw + (size_t)(bn + 64 + sr) * K + k0 + 32 + sq * 8);
    }
    short8 af[FI], bf[4];
#pragma unroll
    for (int f = 0; f < FI; f++) af[f] = *(const short8*)(As + (wm + f * 16 + l15) * 40 + quad * 8);
#pragma unroll
    for (int f = 0; f < 4; f++) bf[f] = *(const short8*)(Bs + (wn + f * 16 + l15) * 40 + quad * 8);
#pragma unroll
    for (int fi = 0; fi < FI; fi++)
#pragma unroll
      for (int fj = 0; fj < 4; fj++)
        acc[fi][fj] = __builtin_amdgcn_mfma_f32_16x16x32_bf16(af[fi], bf[fj], acc[fi][fj], 0, 0, 0);
  }

#pragma unroll
  for (int fi = 0; fi < FI; fi++) {
#pragma unroll
    for (int fj = 0; fj < 4; fj++) {
      int col = bn + wn + fj * 16 + l15;
      float bb = BIAS ? bias[col] : 0.f;
#pragma unroll
      for (int rg = 0; rg < 4; rg++) {
        int row = bm + wm + fi * 16 + quad * 4 + rg;
        float v = acc[fi][fj][rg] + bb;
        if (RES) v += Res[(size_t)row * N + col];
        if (RELU) v = fmaxf(v, 0.f);
        if (OUT_BF16) Cb[(size_t)row * N + col] = f2bf(v);
        else Cf[(size_t)row * N + col] = v;
      }
    }
  }
}

// ---------------- KPROJ with fused LayerNorm (kT must not alias hx) ----------------
__global__ __launch_bounds__(256) void kproj_kernel(const float* __restrict__ hx,
                                                    const float* __restrict__ gma,
                                                    const float* __restrict__ bta,
                                                    const unsigned short* __restrict__ Wcb,
                                                    float* __restrict__ khat,
                                                    float* __restrict__ kT) {
  __shared__ unsigned short As[32 * 40];
  __shared__ unsigned short Bs[256 * 40];
  __shared__ float mus[32], ivs[32];
  int tid = threadIdx.x;
  int wave = tid >> 6, lane = tid & 63;
  int wm = (wave >> 1) * 16, wnh = wave & 1, wn = wnh * 128;
  int quad = lane >> 4, l15 = lane & 15;
  int bm = blockIdx.x * 32;

  // ---- LN stats for rows bm..bm+31 (8 threads per row; 8-lane DPP reduce)
  {
    int row = tid >> 3, jj = tid & 7;
    const float4* hr = (const float4*)(hx + (size_t)(bm + row) * H_ + jj * 32);
    float s = 0.f, sq = 0.f;
#pragma unroll
    for (int q = 0; q < 8; q++) {
      float4 v = hr[q];
      s += (v.x + v.y) + (v.z + v.w);
      sq += (v.x * v.x + v.y * v.y) + (v.z * v.z + v.w * v.w);
    }
    s = dpp_xor_add<0xB1>(s);  sq = dpp_xor_add<0xB1>(sq);
    s = dpp_xor_add<0x4E>(s);  sq = dpp_xor_add<0x4E>(sq);
    s = dpp_xor_add<0x141>(s); sq = dpp_xor_add<0x141>(sq);
    float mu = s * (1.f / H_);
    float var = sq * (1.f / H_) - mu * mu;
    if (jj == 0) { mus[row] = mu; ivs[row] = rsqrtf(var + 1e-5f); }
  }

  floatx4 zero = {0.f, 0.f, 0.f, 0.f};
  floatx4 acc[8];
#pragma unroll
  for (int fj = 0; fj < 8; fj++) acc[fj] = zero;

  int sr = tid >> 2, sq4 = tid & 3;
  float4 af0, af1, gf0, gf1, bt0, bt1;
  uint4 bv[4];
  if (tid < 128) {
    const float4* ap = (const float4*)(hx + (size_t)(bm + sr) * H_ + sq4 * 8);
    af0 = ap[0]; af1 = ap[1];
    const float4* gp = (const float4*)(gma + sq4 * 8); gf0 = gp[0]; gf1 = gp[1];
    const float4* bp = (const float4*)(bta + sq4 * 8); bt0 = bp[0]; bt1 = bp[1];
  }
#pragma unroll
  for (int q = 0; q < 4; q++) {
    int unit = q * 256 + tid;
    bv[q] = *(const uint4*)(Wcb + (size_t)(unit >> 2) * H_ + (unit & 3) * 8);
  }

  for (int k0 = 0; k0 < 256; k0 += 32) {
    __syncthreads();
    if (tid < 128) {  // normalize + cast + stage A
      float mu = mus[sr], iv = ivs[sr];
      ushort4 lo, hi;
      lo.x = f2bf((af0.x - mu) * iv * gf0.x + bt0.x);
      lo.y = f2bf((af0.y - mu) * iv * gf0.y + bt0.y);
      lo.z = f2bf((af0.z - mu) * iv * gf0.z + bt0.z);
      lo.w = f2bf((af0.w - mu) * iv * gf0.w + bt0.w);
      hi.x = f2bf((af1.x - mu) * iv * gf1.x + bt1.x);
      hi.y = f2bf((af1.y - mu) * iv * gf1.y + bt1.y);
      hi.z = f2bf((af1.z - mu) * iv * gf1.z + bt1.z);
      hi.w = f2bf((af1.w - mu) * iv * gf1.w + bt1.w);
      *(ushort4*)(As + sr * 40 + sq4 * 8) = lo;
      *(ushort4*)(As + sr * 40 + sq4 * 8 + 4) = hi;
    }
#pragma unroll
    for (int q = 0; q < 4; q++) {
      int unit = q * 256 + tid;
      *(uint4*)(Bs + (unit >> 2) * 40 + (unit & 3) * 8) = bv[q];
    }
    __syncthreads();
    if (k0 + 32 < 256) {
      if (tid < 128) {
        const float4* ap = (const float4*)(hx + (size_t)(bm + sr) * H_ + k0 + 32 + sq4 * 8);
        af0 = ap[0]; af1 = ap[1];
        const float4* gp = (const float4*)(gma + k0 + 32 + sq4 * 8); gf0 = gp[0]; gf1 = gp[1];
        const float4* bp = (const float4*)(bta + k0 + 32 + sq4 * 8); bt0 = bp[0]; bt1 = bp[1];
      }
#pragma unroll
      for (int q = 0; q < 4; q++) {
        int unit = q * 256 + tid;
        bv[q] = *(const uint4*)(Wcb + (size_t)(unit >> 2) * H_ + k0 + 32 + (unit & 3) * 8);
      }
    }
    short8 af = *(const short8*)(As + (wm + l15) * 40 + quad * 8);
    short8 bf[8];
#pragma unroll
    for (int fj = 0; fj < 8; fj++)
      bf[fj] = *(const short8*)(Bs + (wn + fj * 16 + l15) * 40 + quad * 8);
#pragma unroll
    for (int fj = 0; fj < 8; fj++)
      acc[fj] = __builtin_amdgcn_mfma_f32_16x16x32_bf16(af, bf[fj], acc[fj], 0, 0, 0);
  }

  // epilogue: per-row L2 norm over this wave's 128-col half
  int b = bm >> 9;
  int idxm = b * 2 + wnh;
  int tloc0 = (bm & 511) + wm + quad * 4;
  float inv[4];
#pragma unroll
  for (int rg = 0; rg < 4; rg++) {
    float ssq = 0.f;
#pragma unroll
    for (int fj = 0; fj < 8; fj++) ssq += acc[fj][rg] * acc[fj][rg];
    ssq = redu16(ssq);
    inv[rg] = 1.f / fmaxf(sqrtf(ssq), 1e-12f);
  }
#pragma unroll
  for (int fj = 0; fj < 8; fj++) {
    int ch = fj * 16 + l15;             // logical col 0..127
    int j = ch >> 2, e = ch & 3;        // float4 granule + elem
    int pj = (j & 1) ? (16 + (j >> 1)) : (j >> 1);  // even granules first
    int pcol = pj * 4 + e;
#pragma unroll
    for (int rg = 0; rg < 4; rg++)
      khat[((size_t)idxm * L_ + tloc0 + rg) * HALF_ + pcol] = acc[fj][rg] * inv[rg];
    float4 raw = {acc[fj][0], acc[fj][1], acc[fj][2], acc[fj][3]};
    *(float4*)(kT + (size_t)idxm * (HALF_ * L_) + (size_t)ch * L_ + tloc0) = raw;
  }
}

// ---------------- gram: G1[t] = khat_{t-1}.khat_t, G2[t] = khat_{t-2}.khat_t (per matrix) ----------------
__global__ __launch_bounds__(256) void gram_kernel(const float* __restrict__ khat,
                                                   float* __restrict__ G) {
  int bid = blockIdx.x;
  int im = bid & 31, part = bid >> 5;  // 8 parts x 64 t-values
  int tid = threadIdx.x;
  int seg = tid & 15, rl = tid >> 4;
  const float* kh = khat + (size_t)im * L_ * HALF_ + seg * 8;
  float* g1 = G + im * 1024;
  float* g2 = g1 + 512;
#pragma unroll
  for (int tb = 0; tb < 4; tb++) {
    int t = part * 64 + tb * 16 + rl;
    float a[8], b1[8], b2[8];
    *(float4*)&a[0] = *(const float4*)(kh + (size_t)t * HALF_);
    *(float4*)&a[4] = *(const float4*)(kh + (size_t)t * HALF_ + 4);
    float d1 = 0.f, d2 = 0.f;
    if (t >= 1) {
      *(float4*)&b1[0] = *(const float4*)(kh + (size_t)(t - 1) * HALF_);
      *(float4*)&b1[4] = *(const float4*)(kh + (size_t)(t - 1) * HALF_ + 4);
      d1 = redu16(dot8t(a, b1));
    }
    if (t >= 2) {
      *(float4*)&b2[0] = *(const float4*)(kh + (size_t)(t - 2) * HALF_);
      *(float4*)&b2[4] = *(const float4*)(kh + (size_t)(t - 2) * HALF_ + 4);
      d2 = redu16(dot8t(a, b2));
    }
    if (seg == 0) { g1[t] = d1; g2[t] = d2; }
  }
}

// ---------------- scan: 2-step-lookahead pipelined delta rule ----------------
// p_t = D + s_{t-2}*G2[t] + s_{t-1}*G1[t], D = dot(M_{t-3}, khat_t) issued 2 steps
// early (dot+redu16 off the critical path). m-update deferred 1 step. Ring of 8
// khat rows in registers (slot = t mod 8, 2-step LDS lead). Chunk boundary:
// flush pending update, cold-restart D pipeline (m is then M_{t0-1}, so the
// uniform formula with sp1=sp2=0 is exact). Reassociation-only vs serial rule.

#define UPD8(SL)                                                          \
  do {                                                                    \
    m[0] += sp1 * pk[SL][0]; m[1] += sp1 * pk[SL][1];                     \
    m[2] += sp1 * pk[SL][2]; m[3] += sp1 * pk[SL][3];                     \
    m[4] += sp1 * pk[SL][4]; m[5] += sp1 * pk[SL][5];                     \
    m[6] += sp1 * pk[SL][6]; m[7] += sp1 * pk[SL][7];                     \
  } while (0)

#define PSTEP(SU, SD, KR, G1V, G2V)                                       \
  do {                                                                    \
    UPD8(SU);                                                             \
    float dn_ = redu16(dot8t(m, pk[SD]));                                 \
    float p_ = (pD0 + sp2 * (G2V)) + sp1 * (G1V);                         \
    float s_ = (KR) - p_;                                                 \
    sp2 = sp1; sp1 = s_; pD0 = pD1; pD1 = dn_;                            \
  } while (0)

#define PSTEP_NODN(SU, KR, G1V, G2V)                                      \
  do {                                                                    \
    UPD8(SU);                                                             \
    float p_ = (pD0 + sp2 * (G2V)) + sp1 * (G1V);                         \
    float s_ = (KR) - p_;                                                 \
    sp2 = sp1; sp1 = s_; pD0 = pD1;                                       \
  } while (0)

#define LOADSLOT(S, LT)                                                   \
  do {                                                                    \
    *(float4*)&pk[S][0] = *(const float4*)(bufbase + (LT) * 128);         \
    *(float4*)&pk[S][4] = *(const float4*)(bufbase + (LT) * 128 + 64);    \
  } while (0)

// 8 steps starting at local lt (global T); DO47: do ring loads for j>=4
#define ITER8(LT, T, DO47)                                                \
  do {                                                                    \
    LOADSLOT(4, (LT) + 4);                                                \
    krB = *(const float4*)(krow + (T) + 4);                               \
    g1B = *(const float4*)&gg[(T) + 4];                                   \
    g2B = *(const float4*)&gg[512 + (T) + 4];                             \
    PSTEP(7, 2, krA.x, g1A.x, g2A.x);                                     \
    LOADSLOT(5, (LT) + 5);                                                \
    PSTEP(0, 3, krA.y, g1A.y, g2A.y);                                     \
    LOADSLOT(6, (LT) + 6);                                                \
    PSTEP(1, 4, krA.z, g1A.z, g2A.z);                                     \
    LOADSLOT(7, (LT) + 7);                                                \
    PSTEP(2, 5, krA.w, g1A.w, g2A.w);                                     \
    if (DO47) LOADSLOT(0, (LT) + 8);                                      \
    krA = *(const float4*)(krow + (T) + 8);                               \
    g1A = *(const float4*)&gg[(T) + 8];                                   \
    g2A = *(const float4*)&gg[512 + (T) + 8];                             \
    PSTEP(3, 6, krB.x, g1B.x, g2B.x);                                     \
    if (DO47) LOADSLOT(1, (LT) + 9);                                      \
    PSTEP(4, 7, krB.y, g1B.y, g2B.y);                                     \
    if (DO47) LOADSLOT(2, (LT) + 10);                                     \
    PSTEP(5, 0, krB.z, g1B.z, g2B.z);                                     \
    if (DO47) LOADSLOT(3, (LT) + 11);                                     \
    PSTEP(6, 1, krB.w, g1B.w, g2B.w);                                     \
  } while (0)

__global__ __launch_bounds__(256) void scan_kernel(const float* __restrict__ khat,
                                                   const float* __restrict__ kT,
                                                   const float* __restrict__ G,
                                                   float* __restrict__ c) {
  __shared__ float sk[2][64 * 128];  // 2 x 32 KB double buffer
  __shared__ float gg[1024];         // G1[512] ++ G2[512] for this matrix
  int bid = blockIdx.x;
  int idxm = bid & 31;
  int rg = bid >> 5;
  int b = idxm >> 1, mat = idxm & 1;
  const float* kh = khat + (size_t)idxm * L_ * HALF_;
  const float* kTi = kT + (size_t)idxm * HALF_ * L_;

  int tid = threadIdx.x;
  int wave = tid >> 6, lane = tid & 63;
  int seg = tid & 15, rl = tid >> 4;
  int r = rg * 16 + rl;
  int c0 = seg * 8;
  const float* krow = kTi + (size_t)r * L_;

  float m[8];
#pragma unroll
  for (int g = 0; g < 8; g++) m[g] = 0.f;

  // prologue: stage chunk 0 (async) + G into LDS; one barrier
  {
    const float* g0 = kh + wave * 2048 + lane * 4;
    float* l0 = &sk[0][wave * 2048];
#pragma unroll
    for (int j = 0; j < 8; j++) async_cp16(g0 + j * 256, l0 + j * 256);
    *(float4*)(gg + tid * 4) = *(const float4*)(G + idxm * 1024 + tid * 4);
  }
  __syncthreads();

  const float* lb = &sk[0][0] + seg * 4;
  const float* bufbase = lb;
  float pk[8][8];
  float pD0 = 0.f, pD1 = 0.f, sp1 = 0.f, sp2 = 0.f;
  float4 krA, krB, g1A, g1B, g2A, g2B;
  krA = *(const float4*)(krow);
  g1A = *(const float4*)&gg[0];
  g2A = *(const float4*)&gg[512];
  LOADSLOT(0, 0); LOADSLOT(1, 1); LOADSLOT(2, 2); LOADSLOT(3, 3);

  for (int ch = 0; ch < 8; ch++) {
    bufbase = lb + (ch & 1) * 8192;
    if (ch < 7) {  // stage next chunk (drains at end-of-chunk barrier)
      const float* gs = kh + (size_t)(ch + 1) * 8192 + wave * 2048 + lane * 4;
      float* ls = &sk[(ch + 1) & 1][wave * 2048];
#pragma unroll
      for (int j = 0; j < 8; j++) async_cp16(gs + j * 256, ls + j * 256);
    }
    if (ch > 0) {
      // boundary: flush pending update (s of last step, kp in slot 7 = prev row 63),
      // reload slots 0..3 from the new buffer, cold-restart D pipeline.
      UPD8(7);
      LOADSLOT(0, 0); LOADSLOT(1, 1); LOADSLOT(2, 2); LOADSLOT(3, 3);
      pD0 = redu16(dot8t(m, pk[0]));
      pD1 = redu16(dot8t(m, pk[1]));
      sp1 = 0.f; sp2 = 0.f;
    }
    int T0 = ch * 64;
    for (int it = 0; it < 7; ++it) {
      int lt = it * 8;
      ITER8(lt, T0 + lt, 1);
    }
    if (ch < 7) {
      ITER8(56, T0 + 56, 0);  // last 8 steps of chunk; skip cross-chunk ring loads
    } else {
      // tail: global steps 504..510 (local 56..62), then final flush
      LOADSLOT(4, 60);
      krB = *(const float4*)(krow + 508);
      g1B = *(const float4*)&gg[508];
      g2B = *(const float4*)&gg[512 + 508];
      PSTEP(7, 2, krA.x, g1A.x, g2A.x);   // 504
      LOADSLOT(5, 61);
      PSTEP(0, 3, krA.y, g1A.y, g2A.y);   // 505
      LOADSLOT(6, 62);
      PSTEP(1, 4, krA.z, g1A.z, g2A.z);   // 506
      PSTEP(2, 5, krA.w, g1A.w, g2A.w);   // 507
      PSTEP(3, 6, krB.x, g1B.x, g2B.x);   // 508 (Dn for 510 uses row 62)
      PSTEP_NODN(4, krB.y, g1B.y, g2B.y); // 509
      PSTEP_NODN(5, krB.z, g1B.z, g2B.z); // 510
      UPD8(6);                            // flush s_510 * kp_510 (slot 6 = row 62)
    }
    __syncthreads();
  }

  // final read with raw last-token key (t=511), gathered from kT columns
  float q[8];
#pragma unroll
  for (int j = 0; j < 8; j++) q[j] = kTi[(size_t)(c0 + j) * L_ + 511];
  float p = redu16(dot8t(m, q));
  if (seg == 0) c[(size_t)b * H_ + mat * HALF_ + r] = p;
}

// ---------------- r = c @ W_rp^T + b_rp ----------------
__global__ void rp_kernel(const float* __restrict__ c, const float* __restrict__ Wrp,
                          const float* __restrict__ brp, float* __restrict__ r) {
  int b = blockIdx.x;
  int n = threadIdx.x;  // 256
  __shared__ float cs[H_];
  cs[n] = c[(size_t)b * H_ + n];
  __syncthreads();
  const float4* w4 = (const float4*)(Wrp + (size_t)n * H_);
  const float4* c4 = (const float4*)cs;
  float acc = 0.f;
#pragma unroll 8
  for (int k = 0; k < H_ / 4; k++) {
    float4 w = w4[k], cc = c4[k];
    acc += w.x * cc.x + w.y * cc.y + w.z * cc.z + w.w * cc.w;
  }
  r[(size_t)b * H_ + n] = acc + brp[n];
}

// ---------------- out = r @ W_out^T + b_out, coalesced (R6-proven) ----------------
__global__ __launch_bounds__(256) void out_kernel(const float* __restrict__ r,
                                                  const float* __restrict__ Wout,
                                                  const float* __restrict__ bout,
                                                  float* __restrict__ out) {
  __shared__ float rs[16 * 272];
  __shared__ float obuf[16 * 68];
  int tid = threadIdx.x;
#pragma unroll
  for (int q = 0; q < 16; q++) {
    int idx = q * 256 + tid;
    int bb = idx >> 8, cc = idx & 255;
    rs[bb * 272 + cc + 4 * (cc >> 6)] = r[idx];
  }
  __syncthreads();
  int row = tid >> 2, part = tid & 3;
  int v = blockIdx.x * 64 + row;
  const float4* w4 = (const float4*)(Wout + (size_t)v * H_ + part * 64);
  float acc[16];
#pragma unroll
  for (int bb = 0; bb < 16; bb++) acc[bb] = 0.f;
#pragma unroll 4
  for (int j = 0; j < 16; j++) {
    float4 w = w4[j];
#pragma unroll
    for (int bb = 0; bb < 16; bb++) {
      float4 rv = *(const float4*)&rs[bb * 272 + part * 68 + j * 4];
      acc[bb] += w.x * rv.x + w.y * rv.y + w.z * rv.z + w.w * rv.w;
    }
  }
  float bo = bout[v];
#pragma unroll
  for (int bb = 0; bb < 16; bb++) {
    acc[bb] = dpp_xor_add<0xB1>(acc[bb]);
    acc[bb] = dpp_xor_add<0x4E>(acc[bb]);
  }
#pragma unroll
  for (int q = 0; q < 4; q++) {
    int bb = part * 4 + q;
    obuf[bb * 68 + row] = acc[bb] + bo;
  }
  __syncthreads();
#pragma unroll
  for (int q = 0; q < 4; q++) {
    int idx = q * 256 + tid;
    int bb = idx >> 6, vl = idx & 63;
    out[(size_t)bb * V_ + blockIdx.x * 64 + vl] = obuf[bb * 68 + vl];
  }
}

extern "C" void kernel_launch(void* const* d_in, const int* in_sizes, int n_in,
                              void* d_out, int out_size, void* d_ws, size_t ws_size,
                              hipStream_t stream) {
  const int* seq = (const int*)d_in[0];
  const float* embed = (const float*)d_in[1];
  const float* W1 = (const float*)d_in[2];
  const float* b1 = (const float*)d_in[3];
  const float* W2 = (const float*)d_in[4];
  const float* b2 = (const float*)d_in[5];
  const float* gamma = (const float*)d_in[6];
  const float* beta = (const float*)d_in[7];
  const float* Wsem = (const float*)d_in[8];
  const float* Wepi = (const float*)d_in[9];
  const float* Wrp = (const float*)d_in[10];
  const float* brp = (const float*)d_in[11];
  const float* Wout = (const float*)d_in[12];
  const float* bout = (const float*)d_in[13];
  float* out = (float*)d_out;

  // Workspace layout (float-slot offsets) — alias-free schedule:
  //  [0        , 2097152 )  h fp32 (x in-place; read by gemm2 Res and kproj hx)
  //  [2097152  , 4194304 )  a1b bf16 -> later khat (a1b dead after gemm2)
  //  [4194304  , 5242880 )  hbf bf16 (dead after gemm1)
  //  [4194304  , 6291456 )  kT fp32 [32,128,512] (over dead hbf+gap; NOT aliasing h)
  //  [6291456  , 6356992 )  W1b
  //  [6356992  , 6422528 )  W2b
  //  [6422528  , 6455296 )  Wcb
  //  [6455296  , 6459392 )  c  [16,256]
  //  [6459392  , 6463488 )  r  [16,256]
  //  [6463488  , 6496256 )  G  [32][2][512] gram tables
  float* ws = (float*)d_ws;
  float* h = ws;
  unsigned short* a1b = (unsigned short*)(ws + 2097152);
  float* khat = ws + 2097152;
  unsigned short* hbf = (unsigned short*)(ws + 4194304);
  float* kT = ws + 4194304;
  unsigned short* W1b = (unsigned short*)(ws + 6291456);
  unsigned short* W2b = (unsigned short*)(ws + 6356992);
  unsigned short* Wcb = (unsigned short*)(ws + 6422528);
  float* c = ws + 6455296;
  float* r = ws + 6459392;
  float* G = ws + 6463488;

  // 1. gather (h fp32 + hbf bf16) + weight conversion
  prep_kernel<<<3328, 256, 0, stream>>>(seq, embed, h, hbf, W1, W2, Wsem, Wepi, W1b, W2b, Wcb);
  // 2. a1 = relu(h @ W1^T + b1) -> bf16
  gemm_mfma<128, true, true, false, true><<<dim3(4, 64), 256, 0, stream>>>(
      hbf, W1b, b1, nullptr, nullptr, a1b, 8192, 512, 256);
  // 3. x = a1 @ W2^T + b2 + h -> fp32 in-place over h
  gemm_mfma<64, false, true, true, false><<<dim3(2, 128), 256, 0, stream>>>(
      a1b, W2b, b2, h, h, nullptr, 8192, 256, 512);
  // 4+5. fused LayerNorm + k-projection + normalize + permute/transpose
  kproj_kernel<<<256, 256, 0, stream>>>(h, gamma, beta, Wcb, khat, kT);
  // 5.5 gram tables for the pipelined scan
  gram_kernel<<<256, 256, 0, stream>>>(khat, G);
  // 6. delta-rule scan -> c [16,256]
  scan_kernel<<<256, 256, 0, stream>>>(khat, kT, G, c);
  // 7. r = c @ Wrp^T + brp
  rp_kernel<<<16, 256, 0, stream>>>(c, Wrp, brp, r);
  // 8. out = r @ Wout^T + bout
  out_kernel<<<500, 256, 0, stream>>>(r, Wout, bout, out);
}